// Round 10
// baseline (231.389 us; speedup 1.0000x reference)
//
#include <hip/hip_runtime.h>
#include <hip/hip_bf16.h>
#include <math.h>

constexpr int B_ = 8;
constexpr int C_ = 256;
constexpr int N_ = 2048;
constexpr int CN_ = C_ * N_;        // 524288
constexpr int TOT_ = B_ * C_ * N_;  // 4194304
constexpr int BN_ = B_ * N_;        // 16384
constexpr int NTILES = 16;          // 128-wide strips
constexpr int NPAIRS = 136;         // triangular tiles per batch
constexpr float EPS_SUM = 256.0f * 1e-6f;
constexpr float RESCUE_T = 0.015f;  // v-units; > deterministic fp16 hi*hi err bound

typedef __attribute__((ext_vector_type(8))) _Float16 f16x8;
typedef __attribute__((ext_vector_type(4))) float f32x4;

__device__ __forceinline__ void g2l16(const void* g, void* l) {
    __builtin_amdgcn_global_load_lds(
        (const __attribute__((address_space(1))) void*)g,
        (__attribute__((address_space(3))) void*)l, 16, 0, 0);
}

__device__ __forceinline__ unsigned short hbits(_Float16 h) {
    union { _Float16 h; unsigned short u; } cv;
    cv.h = h;
    return cv.u;
}

// sum of 4 per-ctile norm partials -> reciprocal norm (exact fp32 norms)
__device__ __forceinline__ float rnorm_at(const float* __restrict__ np, int idx) {
    return 1.0f / sqrtf(np[idx] + np[BN_ + idx] + np[2 * BN_ + idx] +
                        np[3 * BN_ + idx] + EPS_SUM);
}

// ----------------------------------------- convert (+ norm partials) -------
// grid = 1024, 256 thr. 64c x 64n tile: transpose, fp16 cast, norm partial.
// Block 0 zeroes the per-batch rescue counters.
__global__ __launch_bounds__(256) void convert_kernel(const float* __restrict__ x,
                                                      _Float16* __restrict__ hiT,
                                                      float* __restrict__ normpart,
                                                      int* __restrict__ rcnt8) {
    const int blk = blockIdx.x;
    const int nt = blk & 31, ctile = (blk >> 5) & 3, batch = blk >> 7;
    const int n0 = nt << 6, c0 = ctile << 6;
    const int t = threadIdx.x;
    const int i = t & 63, j = t >> 6;

    if (blk == 0 && t < 8) rcnt8[t] = 0;

    __shared__ float tb[64][65];
    __shared__ float red[4][64];

    float s = 0.f;
    const float* xp = x + (size_t)batch * CN_ + (size_t)c0 * N_ + n0 + i;
#pragma unroll 4
    for (int r = 0; r < 16; ++r) {
        const int cl = j + r * 4;
        const float v = xp[(size_t)cl * N_];
        tb[cl][i] = v;
        s += v * v;
    }
    red[j][i] = s;
    __syncthreads();

    const int cp = t & 31;
    const int c2 = cp << 1;
    const int nb = t >> 5;
#pragma unroll 4
    for (int r = 0; r < 8; ++r) {
        const int n = nb + r * 8;
        const float v0 = tb[c2][n], v1 = tb[c2 + 1][n];
        const size_t o = ((size_t)batch * N_ + n0 + n) * C_ + c0 + c2;
        const _Float16 h0 = (_Float16)v0;
        const _Float16 h1 = (_Float16)v1;
        ((unsigned*)hiT)[o >> 1] = ((unsigned)hbits(h1) << 16) | hbits(h0);
    }
    if (j == 0) {
        const float tt = red[0][i] + red[1][i] + red[2][i] + red[3][i];
        normpart[ctile * BN_ + batch * N_ + n0 + i] = tt;
    }
}

// ------------------------------- gram (MFMA fp16 hi*hi) + argmax -----------
// grid = B * 136 of 256 thr (4 waves). 128x128 tile, BK=64, XOR-swizzled LDS
// staging. SINGLE segment: fp16(x)*fp16(x) — error bound << RESCUE_T, near
// ties re-checked exactly by rescue. Epilogue arrays overlay As (LDS 32 KB).
__global__ __launch_bounds__(256) void gram_mfma_kernel(
        const _Float16* __restrict__ hiT, const float* __restrict__ normpart,
        float* __restrict__ pval, int* __restrict__ pidx, float* __restrict__ pval2) {
    const int blk = blockIdx.x;
    const int batch = blk / NPAIRS;
    int p = blk - batch * NPAIRS;
    int bn = 0;
    while (p >= NTILES - bn) { p -= NTILES - bn; ++bn; }
    const int bm = bn + p;
    const bool diag = (bn == bm);
    const int n0 = bn << 7, m0 = bm << 7;

    __shared__ short As[128 * 64];
    __shared__ short Bs[128 * 64];
    float (*rv1)[2] = (float(*)[2])(As + 0);
    int (*ri1)[2] = (int(*)[2])(As + 512);
    float (*rv2)[2] = (float(*)[2])(As + 1024);
    float (*cv1)[2] = (float(*)[2])(As + 1536);
    int (*ci1)[2] = (int(*)[2])(As + 2048);
    float (*cv2)[2] = (float(*)[2])(As + 2560);
    float* rnA = (float*)(As + 3072);

    const int tid = threadIdx.x;
    const int l = tid & 63, w = tid >> 6;
    const int lm = l & 15, q = l >> 4;
    const int wn = (w >> 1) << 6, wm = (w & 1) << 6;

    f32x4 acc[4][4];
#pragma unroll
    for (int rt = 0; rt < 4; ++rt)
#pragma unroll
        for (int ct = 0; ct < 4; ++ct) acc[rt][ct] = (f32x4){0.f, 0.f, 0.f, 0.f};

    const size_t bbase = (size_t)batch * CN_;

    for (int kt = 0; kt < 4; ++kt) {
        const int kb = kt << 6;
        __syncthreads();
#pragma unroll
        for (int pp = 0; pp < 4; ++pp) {
            const int slot = tid + pp * 256;
            const int r = slot >> 3, sidx = slot & 7;
            const int sw = sidx ^ (r & 7);  // XOR swizzle (self-inverse)
            g2l16(hiT + bbase + (size_t)(n0 + r) * C_ + kb + sw * 8, As + slot * 8);
            g2l16(hiT + bbase + (size_t)(m0 + r) * C_ + kb + sw * 8, Bs + slot * 8);
        }
        __syncthreads();
#pragma unroll
        for (int kq = 0; kq < 2; ++kq) {
            f16x8 af[4], bfr[4];
#pragma unroll
            for (int rt = 0; rt < 4; ++rt) {
                const int row = wn + rt * 16 + lm;
                af[rt] = *(const f16x8*)(As + row * 64 + (((kq << 2) | q) ^ (lm & 7)) * 8);
            }
#pragma unroll
            for (int ct = 0; ct < 4; ++ct) {
                const int row = wm + ct * 16 + lm;
                bfr[ct] = *(const f16x8*)(Bs + row * 64 + (((kq << 2) | q) ^ (lm & 7)) * 8);
            }
#pragma unroll
            for (int rt = 0; rt < 4; ++rt)
#pragma unroll
                for (int ct = 0; ct < 4; ++ct)
                    acc[rt][ct] = __builtin_amdgcn_mfma_f32_16x16x32_f16(
                        af[rt], bfr[ct], acc[rt][ct], 0, 0, 0);
        }
    }

    __syncthreads();  // drain LDS reads before overlaying As
    if (tid < 128) rnA[tid] = rnorm_at(normpart, batch * N_ + n0 + tid);

    // ---- row path
    float rnm[4];
#pragma unroll
    for (int ct = 0; ct < 4; ++ct)
        rnm[ct] = rnorm_at(normpart, batch * N_ + m0 + wm + ct * 16 + lm);

#pragma unroll
    for (int rt = 0; rt < 4; ++rt) {
#pragma unroll
        for (int r = 0; r < 4; ++r) {
            const int nrow = n0 + wn + rt * 16 + q * 4 + r;
            float v1 = -3.4e38f, v2 = -3.4e38f;
            int i1 = 0x7fffffff;
#pragma unroll
            for (int ct = 0; ct < 4; ++ct) {
                const int m = m0 + wm + ct * 16 + lm;
                const float v = acc[rt][ct][r] * rnm[ct];
                if (m == nrow) continue;
                if (v > v1) { v2 = v1; v1 = v; i1 = m; }
                else if (v > v2) v2 = v;
            }
#pragma unroll
            for (int d = 1; d < 16; d <<= 1) {
                const float ov1 = __shfl_xor(v1, d, 64);
                const int oi1 = __shfl_xor(i1, d, 64);
                const float ov2 = __shfl_xor(v2, d, 64);
                if (ov1 > v1 || (ov1 == v1 && oi1 < i1)) {
                    v2 = fmaxf(v1, ov2); v1 = ov1; i1 = oi1;
                } else {
                    v2 = fmaxf(v2, ov1);
                }
            }
            if (lm == 0) {
                const int rloc = wn + rt * 16 + q * 4 + r;
                rv1[rloc][w & 1] = v1;
                ri1[rloc][w & 1] = i1;
                rv2[rloc][w & 1] = v2;
            }
        }
    }
    __syncthreads();

    // ---- col path
    if (!diag) {
        float rnn[4][4];
#pragma unroll
        for (int rt = 0; rt < 4; ++rt)
#pragma unroll
            for (int r = 0; r < 4; ++r) rnn[rt][r] = rnA[wn + rt * 16 + q * 4 + r];
#pragma unroll
        for (int ct = 0; ct < 4; ++ct) {
            float v1 = -3.4e38f, v2 = -3.4e38f;
            int i1 = 0x7fffffff;
#pragma unroll
            for (int rt = 0; rt < 4; ++rt) {
#pragma unroll
                for (int r = 0; r < 4; ++r) {
                    const float v = acc[rt][ct][r] * rnn[rt][r];
                    const int nn = n0 + wn + rt * 16 + q * 4 + r;
                    if (v > v1) { v2 = v1; v1 = v; i1 = nn; }
                    else if (v > v2) v2 = v;
                }
            }
#pragma unroll
            for (int d = 16; d < 64; d <<= 1) {
                const float ov1 = __shfl_xor(v1, d, 64);
                const int oi1 = __shfl_xor(i1, d, 64);
                const float ov2 = __shfl_xor(v2, d, 64);
                if (ov1 > v1 || (ov1 == v1 && oi1 < i1)) {
                    v2 = fmaxf(v1, ov2); v1 = ov1; i1 = oi1;
                } else {
                    v2 = fmaxf(v2, ov1);
                }
            }
            if (q == 0) {
                const int mloc = wm + ct * 16 + lm;
                cv1[mloc][w >> 1] = v1;
                ci1[mloc][w >> 1] = i1;
                cv2[mloc][w >> 1] = v2;
            }
        }
    }
    __syncthreads();

    if (tid < 128) {
        {
            float v1 = rv1[tid][0]; int i1 = ri1[tid][0]; float v2 = rv2[tid][0];
            const float ov1 = rv1[tid][1]; const int oi1 = ri1[tid][1]; const float ov2 = rv2[tid][1];
            if (ov1 > v1 || (ov1 == v1 && oi1 < i1)) { v2 = fmaxf(v1, ov2); v1 = ov1; i1 = oi1; }
            else v2 = fmaxf(v2, ov1);
            const size_t gi = (size_t)(batch * NTILES + bm) * N_ + n0 + tid;
            pval[gi] = v1; pidx[gi] = i1; pval2[gi] = v2;
        }
        if (!diag) {
            float v1 = cv1[tid][0]; int i1 = ci1[tid][0]; float v2 = cv2[tid][0];
            const float ov1 = cv1[tid][1]; const int oi1 = ci1[tid][1]; const float ov2 = cv2[tid][1];
            if (ov1 > v1 || (ov1 == v1 && oi1 < i1)) { v2 = fmaxf(v1, ov2); v1 = ov1; i1 = oi1; }
            else v2 = fmaxf(v2, ov1);
            const size_t gi = (size_t)(batch * NTILES + bn) * N_ + m0 + tid;
            pval[gi] = v1; pidx[gi] = i1; pval2[gi] = v2;
        }
    }
}

// -------------------------------------------------------------- combine ----
__global__ void combine_kernel(const float* __restrict__ pval, const int* __restrict__ pidx,
                               const float* __restrict__ pval2, int* __restrict__ fidx,
                               int* __restrict__ rcnt8, int* __restrict__ ridx8) {
    const int t = blockIdx.x * 256 + threadIdx.x;  // 16384
    const int batch = t >> 11, n = t & 2047;
    float v1 = -3.4e38f, v2 = -3.4e38f;
    int i1 = 0x7fffffff;
    for (int s = 0; s < NTILES; ++s) {
        const size_t gi = (size_t)(batch * NTILES + s) * N_ + n;
        const float ov1 = pval[gi]; const int oi1 = pidx[gi]; const float ov2 = pval2[gi];
        if (ov1 > v1 || (ov1 == v1 && oi1 < i1)) { v2 = fmaxf(v1, ov2); v1 = ov1; i1 = oi1; }
        else v2 = fmaxf(v2, ov1);
    }
    fidx[t] = i1;
    if (v1 - v2 < RESCUE_T) {
        const int slot = atomicAdd(rcnt8 + batch, 1);
        ridx8[batch * 2048 + slot] = n;
    }
}

// --------------------------------------------------------------- rescue ----
// Exact fp32 re-argmax for flagged rows, BATCHED: 8 rows/block share one
// coalesced stream of x[batch]. grid = 8 batches x 32 slots = 256 blocks.
__global__ __launch_bounds__(256) void rescue_kernel(const float* __restrict__ x,
                                                     const float* __restrict__ normpart,
                                                     const int* __restrict__ rcnt8,
                                                     const int* __restrict__ ridx8,
                                                     int* __restrict__ fidx) {
    const int batch = blockIdx.x & 7;
    const int slot = blockIdx.x >> 3;  // 0..31
    const int cnt = rcnt8[batch];
    if (slot * 8 >= cnt) return;
    const int tid = threadIdx.x;
    const float* xb = x + (size_t)batch * CN_;

    __shared__ int nrs[8];
    __shared__ float xn[8][258];
    __shared__ float bvs[8][257];
    __shared__ int bis[8][257];

    for (int base = slot * 8; base < cnt; base += 32 * 8) {
        if (tid < 8)
            nrs[tid] = (base + tid < cnt) ? ridx8[batch * 2048 + base + tid] : -1;
        __syncthreads();
        // stage the 8 pivot rows x[:, n_g]
        for (int idx = tid; idx < 2048; idx += 256) {
            const int g = idx & 7, c = idx >> 3;
            const int n = nrs[g];
            xn[g][c] = (n >= 0) ? xb[(size_t)c * N_ + n] : 0.f;
        }
        __syncthreads();

        float s[8][8];
#pragma unroll
        for (int g = 0; g < 8; ++g)
#pragma unroll
            for (int k = 0; k < 8; ++k) s[g][k] = 0.f;

        for (int c = 0; c < C_; ++c) {
            const float* xr = xb + (size_t)c * N_;
            float xv[8];
#pragma unroll
            for (int k = 0; k < 8; ++k) xv[k] = xr[tid + (k << 8)];
#pragma unroll
            for (int g = 0; g < 8; ++g) {
                const float xc = xn[g][c];
#pragma unroll
                for (int k = 0; k < 8; ++k) s[g][k] += xc * xv[k];
            }
        }

        float rnl[8];
#pragma unroll
        for (int k = 0; k < 8; ++k) rnl[k] = rnorm_at(normpart, batch * N_ + tid + (k << 8));

#pragma unroll
        for (int g = 0; g < 8; ++g) {
            const int n = nrs[g];
            float best = -3.4e38f;
            int besti = 0x7fffffff;
#pragma unroll
            for (int k = 0; k < 8; ++k) {
                const int m = tid + (k << 8);
                const float v = s[g][k] * rnl[k];
                if (m != n && v > best) { best = v; besti = m; }
            }
            bvs[g][tid] = best;
            bis[g][tid] = besti;
        }
        __syncthreads();
        for (int st = 128; st > 0; st >>= 1) {
            if (tid < st) {
#pragma unroll
                for (int g = 0; g < 8; ++g) {
                    const float ov = bvs[g][tid + st];
                    const int oi = bis[g][tid + st];
                    if (ov > bvs[g][tid] || (ov == bvs[g][tid] && oi < bis[g][tid])) {
                        bvs[g][tid] = ov;
                        bis[g][tid] = oi;
                    }
                }
            }
            __syncthreads();
        }
        if (tid < 8 && nrs[tid] >= 0) fidx[batch * N_ + nrs[tid]] = bis[tid][0];
        __syncthreads();
    }
}

// ------------------------------- finish: gate softmax + gather + outputs ---
// grid = 1024 (batch = blk&7, 128 ntiles of 16 n), 256 thr. f_re from fp16 hi.
__global__ __launch_bounds__(256) void finish_kernel(const float* __restrict__ x,
                                                     const _Float16* __restrict__ hiT,
                                                     const float* __restrict__ W,
                                                     const int* __restrict__ fidx,
                                                     float* __restrict__ out) {
    const int batch = blockIdx.x & 7;
    const int nt = blockIdx.x >> 3;  // 0..127
    const int n0 = nt << 4;
    const int t = threadIdx.x;
    const int i = t & 15, cg = t >> 4;

    __shared__ float Wl[1024];
    __shared__ int il[16];
    __shared__ float l0r[16][17], l1r[16][17];
    __shared__ float w0s[16], w1s[16];

    for (int u = t; u < 1024; u += 256) Wl[u] = W[u];
    if (t < 16) il[t] = fidx[batch * N_ + n0 + t];
    __syncthreads();

    const float* xb = x + (size_t)batch * CN_ + n0 + i;
    const int myidx = il[i];
    const size_t row = ((size_t)batch * N_ + myidx) * C_ + cg * 16;

    float fvv[16];
    {
        const f16x8* hp = (const f16x8*)(hiT + row);
        const f16x8 h0 = hp[0], h1 = hp[1];
#pragma unroll
        for (int e = 0; e < 8; ++e) {
            fvv[e] = (float)h0[e];
            fvv[8 + e] = (float)h1[e];
        }
    }

    float l0 = 0.f, l1 = 0.f;
#pragma unroll
    for (int cc = 0; cc < 16; ++cc) {
        const int c = cg * 16 + cc;
        const float xv = xb[(size_t)c * N_];
        l0 += xv * Wl[c] + fvv[cc] * Wl[256 + c];
        l1 += xv * Wl[512 + c] + fvv[cc] * Wl[768 + c];
    }
    l0r[cg][i] = l0;
    l1r[cg][i] = l1;
    __syncthreads();
    if (t < 16) {
        float L0 = 0.f, L1 = 0.f;
#pragma unroll
        for (int g = 0; g < 16; ++g) { L0 += l0r[g][t]; L1 += l1r[g][t]; }
        const float mx = fmaxf(L0, L1);
        const float e0 = expf(L0 - mx);
        const float e1 = expf(L1 - mx);
        const float inv = 1.0f / (e0 + e1);
        w0s[t] = e0 * inv;
        w1s[t] = e1 * inv;
    }
    __syncthreads();
    const float w0 = w0s[i], w1 = w1s[i];

#pragma unroll
    for (int cc = 0; cc < 16; ++cc) {
        const int c = cg * 16 + cc;
        const size_t off = (size_t)batch * CN_ + (size_t)c * N_ + n0 + i;
        const float xv = xb[(size_t)c * N_];
        out[off] = xv * w0 + fvv[cc] * w1;
        out[TOT_ + off] = fvv[cc];
    }
}

// ---------------------------------------------------------------------------
extern "C" void kernel_launch(void* const* d_in, const int* in_sizes, int n_in,
                              void* d_out, int out_size, void* d_ws, size_t ws_size,
                              hipStream_t stream) {
    const float* x = (const float*)d_in[0];
    const float* W = (const float*)d_in[1];
    float* out = (float*)d_out;

    const size_t HF_BYTES = (size_t)TOT_ * 2;             // 8.39 MB
    const size_t NORM_BYTES = (size_t)BN_ * 4;            // 64 KB
    const size_t P_BYTES = (size_t)B_ * NTILES * N_ * 4;  // 1 MB each

    uint8_t* p = (uint8_t*)d_ws;
    _Float16* hiT = (_Float16*)p; p += HF_BYTES;
    float* normpart = (float*)p; p += 4 * NORM_BYTES;     // per-ctile partials
    float* pval = (float*)p; p += P_BYTES;
    int* pidx = (int*)p; p += P_BYTES;
    float* pval2 = (float*)p; p += P_BYTES;
    int* fidx = (int*)p; p += NORM_BYTES;
    int* rcnt8 = (int*)p; p += 256;
    int* ridx8 = (int*)p; p += 8 * 2048 * 4;

    convert_kernel<<<1024, 256, 0, stream>>>(x, hiT, normpart, rcnt8);
    gram_mfma_kernel<<<B_ * NPAIRS, 256, 0, stream>>>(hiT, normpart, pval, pidx, pval2);
    combine_kernel<<<64, 256, 0, stream>>>(pval, pidx, pval2, fidx, rcnt8, ridx8);
    rescue_kernel<<<256, 256, 0, stream>>>(x, normpart, rcnt8, ridx8, fidx);
    finish_kernel<<<1024, 256, 0, stream>>>(x, hiT, W, fidx, out);
}